// Round 1
// baseline (135.422 us; speedup 1.0000x reference)
//
#include <hip/hip_runtime.h>
#include <hip/hip_bf16.h>
#include <math.h>

#define N_NODES 4096
#define F_IN    512
#define HID     64
#define H       8
#define NJ      512   // H*HID
#define ALPHA   0.2f

typedef __bf16 bf16x8 __attribute__((ext_vector_type(8)));
typedef float  f32x4  __attribute__((ext_vector_type(4)));

// ---------------- Kernel 0: W -> transposed bf16 (Bth[j][k], j=h*64+d) --------
#define B_UNITS (NJ * F_IN)

__global__ __launch_bounds__(256) void conv_w(const float* __restrict__ W,
                                              __bf16* __restrict__ Bth) {
    int bid = blockIdx.x * 256 + threadIdx.x;
    int k = bid & (F_IN - 1);
    int j = bid >> 9;
    float v = W[(size_t)(j >> 6) * F_IN * HID + (size_t)k * HID + (j & 63)];
    Bth[(size_t)j * F_IN + k] = (__bf16)v;
}

// ---------------- Kernel 1: Wh GEMM, fused fp32->split-bf16 staging -----------
// A (=x) is staged straight from fp32 and split hi/lo in-register: same global
// bytes as reading Ah+Al (2x bf16 == fp32), kills the conv_prep round-trip.
// Block remap: blockIdx%8 == XCD (HW round-robin), so the 8 head-blocks of one
// bm run consecutively on ONE XCD -> x tile is L2-resident for 7/8 reads.
__global__ __launch_bounds__(256) void wh_gemm_fused(const float* __restrict__ x,
                                                     const __bf16* __restrict__ Bth,
                                                     const float* __restrict__ a,
                                                     __bf16* __restrict__ Whb,
                                                     float* __restrict__ esrc,
                                                     float* __restrict__ edst) {
    const int bid = blockIdx.x;           // 0..511
    const int xcd = bid & 7;
    const int s0  = bid >> 3;             // 0..63
    const int bm  = xcd * 8 + (s0 >> 3);  // 0..63  (8 bm per XCD)
    const int h   = s0 & 7;               // 0..7   (heads consecutive per bm)

    const int tid  = threadIdx.x;
    const int wave = tid >> 6;
    const int lane = tid & 63;
    const int lm = lane & 15;
    const int lq = lane >> 4;

    __shared__ __align__(16) __bf16 As_h[64][72];
    __shared__ __align__(16) __bf16 As_l[64][72];
    __shared__ __align__(16) __bf16 Bs_h[64][72];

    f32x4 acc[4];
    #pragma unroll
    for (int c = 0; c < 4; c++) acc[c] = (f32x4){0.f, 0.f, 0.f, 0.f};

    for (int k0 = 0; k0 < F_IN; k0 += 64) {
        // stage A: 64x64 fp32 -> split bf16 hi/lo (8 k-elems per thread-unit)
        #pragma unroll
        for (int s = 0; s < 2; s++) {
            int idx = tid + s * 256;          // 0..511
            int m  = idx >> 3;                // 0..63
            int kk = (idx & 7) << 3;          // 0..56
            const float4* gp = (const float4*)(x + (size_t)(bm * 64 + m) * F_IN + k0 + kk);
            float4 v0 = gp[0];
            float4 v1 = gp[1];
            float vv[8] = {v0.x, v0.y, v0.z, v0.w, v1.x, v1.y, v1.z, v1.w};
            bf16x8 hv, lv;
            #pragma unroll
            for (int e = 0; e < 8; e++) {
                __bf16 hi = (__bf16)vv[e];
                hv[e] = hi;
                lv[e] = (__bf16)(vv[e] - (float)hi);
            }
            *(bf16x8*)&As_h[m][kk] = hv;
            *(bf16x8*)&As_l[m][kk] = lv;
            // stage B: 64x64 bf16 tile, plain vector copy
            *(uint4*)&Bs_h[m][kk] = *(const uint4*)(Bth + (size_t)(h * 64 + m) * F_IN + k0 + kk);
        }
        __syncthreads();

        #pragma unroll
        for (int kh = 0; kh < 2; kh++) {
            bf16x8 afh = *(const bf16x8*)&As_h[wave * 16 + lm][kh * 32 + lq * 8];
            bf16x8 afl = *(const bf16x8*)&As_l[wave * 16 + lm][kh * 32 + lq * 8];
            bf16x8 bh[4];
            #pragma unroll
            for (int c = 0; c < 4; c++) {
                bh[c] = *(const bf16x8*)&Bs_h[c * 16 + lm][kh * 32 + lq * 8];
            }
            #pragma unroll
            for (int c = 0; c < 4; c++) {
                acc[c] = __builtin_amdgcn_mfma_f32_16x16x32_bf16(afh, bh[c], acc[c], 0, 0, 0);
                acc[c] = __builtin_amdgcn_mfma_f32_16x16x32_bf16(afl, bh[c], acc[c], 0, 0, 0);
            }
        }
        __syncthreads();
    }

    float a1c[4], a2c[4];
    #pragma unroll
    for (int c = 0; c < 4; c++) {
        a1c[c] = a[h * 2 * HID + c * 16 + lm];
        a2c[c] = a[h * 2 * HID + HID + c * 16 + lm];
    }

    #pragma unroll
    for (int r = 0; r < 4; r++) {
        int row = bm * 64 + wave * 16 + lq * 4 + r;
        float s1 = 0.f, s2 = 0.f;
        #pragma unroll
        for (int c = 0; c < 4; c++) {
            float v = acc[c][r];
            Whb[(size_t)row * NJ + h * HID + c * 16 + lm] = (__bf16)v;
            s1 += v * a1c[c];
            s2 += v * a2c[c];
        }
        #pragma unroll
        for (int o = 1; o < 16; o <<= 1) {
            s1 += __shfl_xor(s1, o);
            s2 += __shfl_xor(s2, o);
        }
        if (lm == 0) {
            esrc[h * N_NODES + row] = s1;
            edst[h * N_NODES + row] = s2;
        }
    }
}

// ---------------- Kernel 2: monolithic gat_attn, 256 threads / row -------------
#define MAXN 128

__global__ __launch_bounds__(256) void gat_attn(const float* __restrict__ adj,
                                                const __bf16* __restrict__ Whb,
                                                const float* __restrict__ esrc,
                                                const float* __restrict__ edst,
                                                float* __restrict__ out) {
    const int i    = blockIdx.x;
    const int tid  = threadIdx.x;
    const int wave = tid >> 6;
    const int lane = tid & 63;
    __shared__ int    nbr[MAXN];
    __shared__ __align__(8)  float2 an[H][MAXN + 4];  // +4 pad: spreads per-h bank aliasing
    __shared__ float  denom[H];
    __shared__ __align__(16) f32x4 part[3][2][64];
    __shared__ int    cnt;

    if (tid == 0) cnt = 0;
    __syncthreads();

    // phase 1: batched ballot compaction; adj streamed NONTEMPORAL so the 67 MB
    // stream does not evict the Whb gather working set from L2.
    const unsigned long long lt = (1ull << lane) - 1ull;
    const f32x4* arow = (const f32x4*)(adj + (size_t)i * N_NODES);
    f32x4 q[4];
    #pragma unroll
    for (int cc = 0; cc < 4; cc++) q[cc] = __builtin_nontemporal_load(arow + cc * 256 + tid);
    #pragma unroll
    for (int cc = 0; cc < 4; cc++) {
        unsigned long long b0 = __ballot(q[cc][0] > 0.f);
        unsigned long long b1 = __ballot(q[cc][1] > 0.f);
        unsigned long long b2 = __ballot(q[cc][2] > 0.f);
        unsigned long long b3 = __ballot(q[cc][3] > 0.f);
        int c0 = __popcll(b0), c1 = __popcll(b1), c2 = __popcll(b2), c3 = __popcll(b3);
        int base = 0;
        if (lane == 0) base = atomicAdd(&cnt, c0 + c1 + c2 + c3);
        base = __shfl(base, 0);
        int col = (cc * 256 + tid) * 4;
        if (q[cc][0] > 0.f) nbr[base + __popcll(b0 & lt)] = col;
        base += c0;
        if (q[cc][1] > 0.f) nbr[base + __popcll(b1 & lt)] = col + 1;
        base += c1;
        if (q[cc][2] > 0.f) nbr[base + __popcll(b2 & lt)] = col + 2;
        base += c2;
        if (q[cc][3] > 0.f) nbr[base + __popcll(b3 & lt)] = col + 3;
    }
    __syncthreads();
    const int n = cnt;

    // phase 2: wave serves heads {2*wave, 2*wave+1}
    #pragma unroll
    for (int k = 0; k < 2; k++) {
        const int hh = wave * 2 + k;
        float es = esrc[hh * N_NODES + i];
        float m = -1e30f;
        for (int j = lane; j < n; j += 64) {
            int c = nbr[j];
            float lg = es + edst[hh * N_NODES + c];
            lg = lg > 0.f ? lg : ALPHA * lg;
            an[hh][j] = make_float2(lg, __int_as_float(c << 10));
            m = fmaxf(m, lg);
        }
        #pragma unroll
        for (int o = 32; o; o >>= 1) m = fmaxf(m, __shfl_xor(m, o));
        float s = 0.f;
        for (int j = lane; j < n; j += 64) {
            float w = __expf(an[hh][j].x - m);
            an[hh][j].x = w;
            s += w;
        }
        #pragma unroll
        for (int o = 32; o; o >>= 1) s += __shfl_xor(s, o);
        if (lane == 0) denom[hh] = s;
    }
    __syncthreads();

    // phase 3: 4 j-streams x 64 dim-threads, uint4 (16B) gathers
    const int qd = tid >> 6;          // 0..3: handles j ≡ qd (mod 4)
    const int t  = tid & 63;          // dim-octet: dims [t*8, t*8+7]
    const int h  = t >> 3;
    const char* wp = (const char*)Whb + t * 16;
    float a0 = 0.f, a1 = 0.f, a2 = 0.f, a3 = 0.f;
    float a4 = 0.f, a5 = 0.f, a6 = 0.f, a7 = 0.f;
    #pragma unroll 4
    for (int j = qd; j < n; j += 4) {
        float2 p = an[h][j];
        uint4 u = *(const uint4*)(wp + __float_as_uint(p.y));
        float w = p.x;
        a0 += w * __uint_as_float(u.x << 16);
        a1 += w * __uint_as_float(u.x & 0xffff0000u);
        a2 += w * __uint_as_float(u.y << 16);
        a3 += w * __uint_as_float(u.y & 0xffff0000u);
        a4 += w * __uint_as_float(u.z << 16);
        a5 += w * __uint_as_float(u.z & 0xffff0000u);
        a6 += w * __uint_as_float(u.w << 16);
        a7 += w * __uint_as_float(u.w & 0xffff0000u);
    }
    if (qd) {
        part[qd - 1][0][t] = (f32x4){a0, a1, a2, a3};
        part[qd - 1][1][t] = (f32x4){a4, a5, a6, a7};
    }
    __syncthreads();
    if (qd == 0) {
        f32x4 r0 = (f32x4){a0, a1, a2, a3};
        f32x4 r1 = (f32x4){a4, a5, a6, a7};
        #pragma unroll
        for (int s = 0; s < 3; s++) {
            r0 += part[s][0][t];
            r1 += part[s][1][t];
        }
        float inv = 1.f / denom[h];
        float b[8];
        #pragma unroll
        for (int e = 0; e < 4; e++) b[e] = r0[e] * inv;
        #pragma unroll
        for (int e = 0; e < 4; e++) b[4 + e] = r1[e] * inv;
        #pragma unroll
        for (int e = 0; e < 8; e++) b[e] = b[e] > 0.f ? b[e] : expm1f(b[e]);
        f32x4 o0 = (f32x4){b[0], b[1], b[2], b[3]};
        f32x4 o1 = (f32x4){b[4], b[5], b[6], b[7]};
        f32x4* op = (f32x4*)(out + (size_t)i * NJ + t * 8);
        __builtin_nontemporal_store(o0, op);
        __builtin_nontemporal_store(o1, op + 1);
    }
}

extern "C" void kernel_launch(void* const* d_in, const int* in_sizes, int n_in,
                              void* d_out, int out_size, void* d_ws, size_t ws_size,
                              hipStream_t stream) {
    const float* x   = (const float*)d_in[0];   // [N, F_IN]
    const float* adj = (const float*)d_in[1];   // [N, N]
    const float* W   = (const float*)d_in[2];   // [H, F_IN, HID]
    const float* a   = (const float*)d_in[3];   // [H, 2*HID]
    float* out = (float*)d_out;                 // [N, H*HID]

    float*  esrc = (float*)d_ws;                              // 32K floats (head-major [h][n])
    float*  edst = esrc + (size_t)H * N_NODES;                // 32K
    __bf16* Whb  = (__bf16*)(edst + (size_t)H * N_NODES);     // 2M bf16 (4 MB)
    __bf16* Bth  = Whb + (size_t)N_NODES * NJ;                // 256K bf16

    conv_w<<<B_UNITS / 256, 256, 0, stream>>>(W, Bth);

    wh_gemm_fused<<<512, 256, 0, stream>>>(x, Bth, a, Whb, esrc, edst);

    gat_attn<<<N_NODES, 256, 0, stream>>>(adj, Whb, esrc, edst, out);
}